// Round 3
// baseline (537.580 us; speedup 1.0000x reference)
//
#include <hip/hip_runtime.h>

// GumbelSlotSelector, round 3: MFMA 3x-bf16-split GEMM, barrier-free steady
// state, software-pipelined A loads, 2-pass (32-row) accumulation to keep
// VGPR ~120 (3 waves/SIMD, 3 blocks/CU at 48 KB LDS).
// One wave == one b (64 rows) so the ensure-minimum fixup is ballot+shuffle.

typedef __attribute__((ext_vector_type(8))) short bf16x8;
typedef __attribute__((ext_vector_type(4))) float f32x4;

constexpr int NROWS = 8192 * 64;   // 524288
constexpr int D = 128;
constexpr int GRID = 1024;         // 2 tiles of 256 rows per block

__device__ __forceinline__ void split3(float x, unsigned& h1, unsigned& h2, unsigned& h3) {
    unsigned ux = __float_as_uint(x);
    h1 = ux & 0xFFFF0000u;                    // top bf16 (truncate)
    float r = x - __uint_as_float(h1);        // exact
    h2 = __float_as_uint(r) & 0xFFFF0000u;    // next 8 mantissa bits
    float r2 = r - __uint_as_float(h2);       // exact
    h3 = __float_as_uint(r2);                 // high 16 used by caller
}

__device__ __forceinline__ void split_pair(float x, float y, int& o1, int& o2, int& o3) {
    unsigned x1, x2, x3, y1, y2, y3;
    split3(x, x1, x2, x3);
    split3(y, y1, y2, y3);
    o1 = (int)((x1 >> 16) | (y1 & 0xFFFF0000u));   // [x bf16 | y bf16]
    o2 = (int)((x2 >> 16) | (y2 & 0xFFFF0000u));
    o3 = (int)((x3 >> 16) | (y3 & 0xFFFF0000u));
}

__global__ __launch_bounds__(256, 3)
void gumbel_slot_mfma(const float* __restrict__ slots,
                      const float* __restrict__ gumbel_u,
                      const float* __restrict__ fix_u,
                      const float* __restrict__ W1,
                      const float* __restrict__ b1,
                      const float* __restrict__ W2,
                      const float* __restrict__ b2,
                      float* __restrict__ out)
{
    // W1 3-split bf16, j-major [plane][j=64][d=128], 16B chunks XOR-swizzled
    // by (j&15) — layout/read path identical to R2 (correctness-proven).
    __shared__ __align__(16) unsigned short wt[3 * 64 * 128];   // 48 KB

    const int tid  = threadIdx.x;
    const int wv   = tid >> 6;
    const int lane = tid & 63;
    const int quad = lane >> 4;
    const int col  = lane & 15;

    // ---- one-time W1 split prep (the only __syncthreads in the kernel) ----
#pragma unroll
    for (int i = 0; i < 32; ++i) {
        const int e = i * 256 + tid;         // e = d*64 + j, coalesced
        const int d = e >> 6, j = e & 63;
        unsigned h1, h2, h3;
        split3(W1[e], h1, h2, h3);
        const int chunk = (d >> 3) ^ (j & 15);
        const int idx = j * 128 + chunk * 8 + (d & 7);
        wt[idx]         = (unsigned short)(h1 >> 16);
        wt[idx + 8192]  = (unsigned short)(h2 >> 16);
        wt[idx + 16384] = (unsigned short)(h3 >> 16);
    }
    __syncthreads();

    float  b1v[4];
    float2 w2v[4];
#pragma unroll
    for (int nt = 0; nt < 4; ++nt) {
        b1v[nt] = b1[nt * 16 + col];
        w2v[nt] = *(const float2*)(W2 + (size_t)(nt * 16 + col) * 2);
    }
    const float2 b2v = *(const float2*)b2;

#pragma unroll 1
    for (int t = 0; t < 2; ++t) {
        const int tile = blockIdx.x + t * GRID;          // 2048 tiles of 256 rows
        const int rowW = tile * 256 + wv * 64;           // this wave's 64 rows
        const int r    = rowW + lane;

        const float2 g2 = *(const float2*)(gumbel_u + (size_t)r * 2);  // early

        // base for this lane's A reads: row (rowW+col), k-offset quad*8
        const float* __restrict__ arow0 = slots + (size_t)(rowW + col) * D + quad * 8;

        float l0 = 0.f, l1 = 0.f;
        float4 raw[2][2];

        // prologue: pass 0, ks 0
#pragma unroll
        for (int mh = 0; mh < 2; ++mh) {
            raw[mh][0] = *(const float4*)(arow0 + mh * 16 * D);
            raw[mh][1] = *(const float4*)(arow0 + mh * 16 * D + 4);
        }

#pragma unroll
        for (int p = 0; p < 2; ++p) {
            f32x4 acc[2][4];
#pragma unroll
            for (int mh = 0; mh < 2; ++mh)
#pragma unroll
                for (int nt = 0; nt < 4; ++nt)
                    acc[mh][nt] = f32x4{0.f, 0.f, 0.f, 0.f};

#pragma unroll
            for (int ks = 0; ks < 4; ++ks) {
                // split raw A -> 3 bf16 fragments (raw dead after this)
                bf16x8 a1[2], a2[2], a3[2];
#pragma unroll
                for (int mh = 0; mh < 2; ++mh) {
                    const float xs[8] = {raw[mh][0].x, raw[mh][0].y, raw[mh][0].z, raw[mh][0].w,
                                         raw[mh][1].x, raw[mh][1].y, raw[mh][1].z, raw[mh][1].w};
                    union { int i[4]; bf16x8 v; } u1, u2, u3;
#pragma unroll
                    for (int q = 0; q < 4; ++q)
                        split_pair(xs[2 * q], xs[2 * q + 1], u1.i[q], u2.i[q], u3.i[q]);
                    a1[mh] = u1.v; a2[mh] = u2.v; a3[mh] = u3.v;
                }

                // prefetch next (ks+1) or next pass's ks0 — overlaps B+MFMA below
                if (ks < 3) {
#pragma unroll
                    for (int mh = 0; mh < 2; ++mh) {
                        raw[mh][0] = *(const float4*)(arow0 + (p * 32 + mh * 16) * D + (ks + 1) * 32);
                        raw[mh][1] = *(const float4*)(arow0 + (p * 32 + mh * 16) * D + (ks + 1) * 32 + 4);
                    }
                } else if (p == 0) {
#pragma unroll
                    for (int mh = 0; mh < 2; ++mh) {
                        raw[mh][0] = *(const float4*)(arow0 + (32 + mh * 16) * D);
                        raw[mh][1] = *(const float4*)(arow0 + (32 + mh * 16) * D + 4);
                    }
                }

                // B fragments from LDS planes + MFMA
#pragma unroll
                for (int nt = 0; nt < 4; ++nt) {
                    const int j = nt * 16 + col;
                    const int chunk = (ks * 4 + quad) ^ col;
                    const unsigned short* wp = &wt[j * 128 + chunk * 8];
                    const bf16x8 bq1 = *(const bf16x8*)(wp);
                    const bf16x8 bq2 = *(const bf16x8*)(wp + 8192);
                    const bf16x8 bq3 = *(const bf16x8*)(wp + 16384);
#pragma unroll
                    for (int mh = 0; mh < 2; ++mh) {
                        f32x4 c = acc[mh][nt];
                        c = __builtin_amdgcn_mfma_f32_16x16x32_bf16(a1[mh], bq1, c, 0, 0, 0);
                        c = __builtin_amdgcn_mfma_f32_16x16x32_bf16(a2[mh], bq1, c, 0, 0, 0);
                        c = __builtin_amdgcn_mfma_f32_16x16x32_bf16(a1[mh], bq2, c, 0, 0, 0);
                        c = __builtin_amdgcn_mfma_f32_16x16x32_bf16(a2[mh], bq2, c, 0, 0, 0);
                        c = __builtin_amdgcn_mfma_f32_16x16x32_bf16(a1[mh], bq3, c, 0, 0, 0);
                        c = __builtin_amdgcn_mfma_f32_16x16x32_bf16(a3[mh], bq1, c, 0, 0, 0);
                        acc[mh][nt] = c;
                    }
                }
            }

            // ---- pass epilogue: layer2 + col-reduction, pure shuffles ----
            // C layout: col(j) = lane&15, local row = mh*16 + quad*4 + reg.
#pragma unroll
            for (int mh = 0; mh < 2; ++mh) {
#pragma unroll
                for (int reg = 0; reg < 4; ++reg) {
                    float p0 = 0.f, p1 = 0.f;
#pragma unroll
                    for (int nt = 0; nt < 4; ++nt) {
                        const float h = fmaxf(acc[mh][nt][reg] + b1v[nt], 0.f);
                        p0 = fmaf(h, w2v[nt].x, p0);
                        p1 = fmaf(h, w2v[nt].y, p1);
                    }
                    // sum over the 16 col-lanes (same quad group)
#pragma unroll
                    for (int m = 1; m <= 8; m <<= 1) {
                        p0 += __shfl_xor(p0, m, 64);
                        p1 += __shfl_xor(p1, m, 64);
                    }
                    // lane wants row=lane: needs source quad (lane>>2)&3
                    const int src = (((lane >> 2) & 3) << 4) | (lane & 15);
                    const float g0 = __shfl(p0, src, 64);
                    const float g1 = __shfl(p1, src, 64);
                    if (((lane >> 5) == p) && (((lane >> 4) & 1) == mh) && ((lane & 3) == reg)) {
                        l0 = g0; l1 = g1;
                    }
                }
            }
        }

        l0 += b2v.x; l1 += b2v.y;

        // ---- gumbel decision + keep prob ----
        const float lo = 1e-10f, hi = (float)(1.0 - 1e-7);
        const float u0 = fminf(fmaxf(g2.x, lo), hi);
        const float u1 = fminf(fmaxf(g2.y, lo), hi);
        const float gn0 = -logf(-logf(u0));
        const float gn1 = -logf(-logf(u1));
        float dec = ((l1 + gn1) > (l0 + gn0)) ? 1.0f : 0.0f;   // tie -> idx0 -> 0

        const float m  = fmaxf(l0, l1);
        const float e0 = expf(l0 - m), e1 = expf(l1 - m);
        const float keep = e1 / (e0 + e1);

        // ensure-minimum: wave == one b; fires only if no slot active
        const unsigned long long act = __ballot(dec != 0.0f);
        if (act == 0ull) {
            float v = fix_u[r];
            int  idx = lane;
#pragma unroll
            for (int off = 32; off > 0; off >>= 1) {
                const float ov  = __shfl_xor(v, off, 64);
                const int  oidx = __shfl_xor(idx, off, 64);
                if (ov > v || (ov == v && oidx < idx)) { v = ov; idx = oidx; }
            }
            if (lane == idx) dec = 1.0f;
        }

        out[r] = dec;
        out[NROWS + r] = keep;
    }
}

extern "C" void kernel_launch(void* const* d_in, const int* in_sizes, int n_in,
                              void* d_out, int out_size, void* d_ws, size_t ws_size,
                              hipStream_t stream)
{
    const float* slots  = (const float*)d_in[0];
    const float* gumbel = (const float*)d_in[1];
    const float* fixu   = (const float*)d_in[2];
    const float* W1     = (const float*)d_in[3];
    const float* b1     = (const float*)d_in[4];
    const float* W2     = (const float*)d_in[5];
    const float* b2     = (const float*)d_in[6];
    float* out = (float*)d_out;

    gumbel_slot_mfma<<<GRID, 256, 0, stream>>>(
        slots, gumbel, fixu, W1, b1, W2, b2, out);
}

// Round 4
// 515.789 us; speedup vs baseline: 1.0422x; 1.0422x over previous
//
#include <hip/hip_runtime.h>

// GumbelSlotSelector R4: MFMA 3x-bf16-split GEMM (exact 6-term fp32 emulation).
// Anti-spill restructure of R3: mt (16-row group) serialized so the live set
// is acc[4] (16 VGPR) + 3 A-frags (12) + 2 prefetch float4 (8) ~= 90 VGPR.
// No dynamically-indexed local arrays anywhere in the hot loop.
// Block 512 (8 waves), 48 KB LDS -> 2 blocks/CU = 16 waves/CU.
// One wave == one b (64 rows): ensure-minimum fixup = ballot + shuffle argmax.

typedef __attribute__((ext_vector_type(8))) short bf16x8;
typedef __attribute__((ext_vector_type(4))) int   i32x4;
typedef __attribute__((ext_vector_type(4))) float f32x4;

constexpr int NROWS = 8192 * 64;   // 524288
constexpr int D = 128;

__device__ __forceinline__ void split3(float x, unsigned& h1, unsigned& h2, unsigned& h3) {
    unsigned ux = __float_as_uint(x);
    h1 = ux & 0xFFFF0000u;                    // top bf16 (truncate) — exact subtract
    float r = x - __uint_as_float(h1);
    h2 = __float_as_uint(r) & 0xFFFF0000u;    // next 8 mantissa bits
    float r2 = r - __uint_as_float(h2);
    h3 = __float_as_uint(r2);                 // remaining bits (high 16 used)
}

__device__ __forceinline__ void split_pair(float x, float y, int& o1, int& o2, int& o3) {
    unsigned x1, x2, x3, y1, y2, y3;
    split3(x, x1, x2, x3);
    split3(y, y1, y2, y3);
    o1 = (int)((x1 >> 16) | (y1 & 0xFFFF0000u));   // [x bf16 | y bf16]
    o2 = (int)((x2 >> 16) | (y2 & 0xFFFF0000u));
    o3 = (int)((x3 >> 16) | (y3 & 0xFFFF0000u));
}

__global__ __launch_bounds__(512, 4)
void gumbel_slot_mfma(const float* __restrict__ slots,
                      const float* __restrict__ gumbel_u,
                      const float* __restrict__ fix_u,
                      const float* __restrict__ W1,
                      const float* __restrict__ b1,
                      const float* __restrict__ W2,
                      const float* __restrict__ b2,
                      float* __restrict__ out)
{
    // W1 3-split bf16, j-major [plane][j=64][d=128], 16B chunks XOR-swizzled
    // by (j&15) — layout/read path identical to R2/R3 (correctness-proven).
    __shared__ __align__(16) unsigned short wt[3 * 64 * 128];   // 48 KB

    const int tid  = threadIdx.x;
    const int wv   = tid >> 6;
    const int lane = tid & 63;
    const int quad = lane >> 4;
    const int col  = lane & 15;

    // ---- one-time W1 split prep (the only __syncthreads in the kernel) ----
#pragma unroll
    for (int i = 0; i < 16; ++i) {
        const int e = i * 512 + tid;         // e = d*64 + j, coalesced
        const int d = e >> 6, j = e & 63;
        unsigned h1, h2, h3;
        split3(W1[e], h1, h2, h3);
        const int chunk = (d >> 3) ^ (j & 15);
        const int idx = j * 128 + chunk * 8 + (d & 7);
        wt[idx]         = (unsigned short)(h1 >> 16);
        wt[idx + 8192]  = (unsigned short)(h2 >> 16);
        wt[idx + 16384] = (unsigned short)(h3 >> 16);
    }
    __syncthreads();

    float  b1v[4];
    float2 w2v[4];
#pragma unroll
    for (int nt = 0; nt < 4; ++nt) {
        b1v[nt] = b1[nt * 16 + col];
        w2v[nt] = *(const float2*)(W2 + (size_t)(nt * 16 + col) * 2);
    }
    const float2 b2v = *(const float2*)b2;

    const int rowW = blockIdx.x * 512 + wv * 64;     // this wave's 64 rows
    const int r    = rowW + lane;

    const float2 g2 = *(const float2*)(gumbel_u + (size_t)r * 2);  // early

    float l0 = 0.f, l1 = 0.f;

    // prologue: prefetch (mt=0, ks=0). Lane reads row rowW+mt*16+col,
    // k = ks*32 + quad*8 .. +8 (two float4s).
    float4 r0 = *(const float4*)(slots + (size_t)(rowW + col) * D + quad * 8);
    float4 r1 = *(const float4*)(slots + (size_t)(rowW + col) * D + quad * 8 + 4);

#pragma unroll
    for (int mt = 0; mt < 4; ++mt) {
        f32x4 acc[4];
#pragma unroll
        for (int nt = 0; nt < 4; ++nt) acc[nt] = f32x4{0.f, 0.f, 0.f, 0.f};

#pragma unroll
        for (int ks = 0; ks < 4; ++ks) {
            // split current raw -> 3 bf16 A-fragments (explicit scalars only)
            int a10, a11, a12, a13, a20, a21, a22, a23, a30, a31, a32, a33;
            split_pair(r0.x, r0.y, a10, a20, a30);
            split_pair(r0.z, r0.w, a11, a21, a31);
            split_pair(r1.x, r1.y, a12, a22, a32);
            split_pair(r1.z, r1.w, a13, a23, a33);
            union { i32x4 i; bf16x8 v; } p1, p2, p3;
            p1.i = i32x4{a10, a11, a12, a13};
            p2.i = i32x4{a20, a21, a22, a23};
            p3.i = i32x4{a30, a31, a32, a33};
            const bf16x8 a1 = p1.v, a2 = p2.v, a3 = p3.v;

            // prefetch next (mt,ks) step — overlaps B reads + MFMAs below
            if (mt * 4 + ks < 15) {
                const int nmt = (ks < 3) ? mt : mt + 1;
                const int nks = (ks < 3) ? ks + 1 : 0;
                const float* np = slots + (size_t)(rowW + nmt * 16 + col) * D
                                        + nks * 32 + quad * 8;
                r0 = *(const float4*)np;
                r1 = *(const float4*)(np + 4);
            }

            // B fragments from LDS planes + 6-term MFMA
#pragma unroll
            for (int nt = 0; nt < 4; ++nt) {
                const int j = nt * 16 + col;
                const int chunk = (ks * 4 + quad) ^ col;
                const unsigned short* wp = &wt[j * 128 + chunk * 8];
                const bf16x8 bq1 = *(const bf16x8*)(wp);
                const bf16x8 bq2 = *(const bf16x8*)(wp + 8192);
                const bf16x8 bq3 = *(const bf16x8*)(wp + 16384);
                f32x4 c = acc[nt];
                c = __builtin_amdgcn_mfma_f32_16x16x32_bf16(a1, bq1, c, 0, 0, 0);
                c = __builtin_amdgcn_mfma_f32_16x16x32_bf16(a2, bq1, c, 0, 0, 0);
                c = __builtin_amdgcn_mfma_f32_16x16x32_bf16(a1, bq2, c, 0, 0, 0);
                c = __builtin_amdgcn_mfma_f32_16x16x32_bf16(a2, bq2, c, 0, 0, 0);
                c = __builtin_amdgcn_mfma_f32_16x16x32_bf16(a1, bq3, c, 0, 0, 0);
                c = __builtin_amdgcn_mfma_f32_16x16x32_bf16(a3, bq1, c, 0, 0, 0);
                acc[nt] = c;
            }
        }

        // ---- mt epilogue: layer2 + col-reduction, pure shuffles ----
        // C layout: col(j) = lane&15, local row = quad*4 + reg (within mt).
#pragma unroll
        for (int reg = 0; reg < 4; ++reg) {
            float q0 = 0.f, q1 = 0.f;
#pragma unroll
            for (int nt = 0; nt < 4; ++nt) {
                const float h = fmaxf(acc[nt][reg] + b1v[nt], 0.f);
                q0 = fmaf(h, w2v[nt].x, q0);
                q1 = fmaf(h, w2v[nt].y, q1);
            }
#pragma unroll
            for (int m = 1; m <= 8; m <<= 1) {
                q0 += __shfl_xor(q0, m, 64);
                q1 += __shfl_xor(q1, m, 64);
            }
            // lane L (row rowW+L) needs mt=L>>4, reg=L&3, from quad (L>>2)&3
            const int src = (((lane >> 2) & 3) << 4) | (lane & 15);
            const float g0 = __shfl(q0, src, 64);
            const float g1 = __shfl(q1, src, 64);
            if (((lane >> 4) == mt) && ((lane & 3) == reg)) { l0 = g0; l1 = g1; }
        }
    }

    l0 += b2v.x; l1 += b2v.y;

    // ---- gumbel decision + keep prob ----
    const float lo = 1e-10f, hi = (float)(1.0 - 1e-7);
    const float u0 = fminf(fmaxf(g2.x, lo), hi);
    const float u1 = fminf(fmaxf(g2.y, lo), hi);
    const float gn0 = -logf(-logf(u0));
    const float gn1 = -logf(-logf(u1));
    float dec = ((l1 + gn1) > (l0 + gn0)) ? 1.0f : 0.0f;   // tie -> idx0 -> 0

    const float m  = fmaxf(l0, l1);
    const float e0 = expf(l0 - m), e1 = expf(l1 - m);
    const float keep = e1 / (e0 + e1);

    // ensure-minimum: wave == one b; fires only if no slot active
    const unsigned long long act = __ballot(dec != 0.0f);
    if (act == 0ull) {
        float v = fix_u[r];
        int  idx = lane;
#pragma unroll
        for (int off = 32; off > 0; off >>= 1) {
            const float ov  = __shfl_xor(v, off, 64);
            const int  oidx = __shfl_xor(idx, off, 64);
            if (ov > v || (ov == v && oidx < idx)) { v = ov; idx = oidx; }
        }
        if (lane == idx) dec = 1.0f;
    }

    out[r] = dec;
    out[NROWS + r] = keep;
}

extern "C" void kernel_launch(void* const* d_in, const int* in_sizes, int n_in,
                              void* d_out, int out_size, void* d_ws, size_t ws_size,
                              hipStream_t stream)
{
    const float* slots  = (const float*)d_in[0];
    const float* gumbel = (const float*)d_in[1];
    const float* fixu   = (const float*)d_in[2];
    const float* W1     = (const float*)d_in[3];
    const float* b1     = (const float*)d_in[4];
    const float* W2     = (const float*)d_in[5];
    const float* b2     = (const float*)d_in[6];
    float* out = (float*)d_out;

    gumbel_slot_mfma<<<1024, 512, 0, stream>>>(
        slots, gumbel, fixu, W1, b1, W2, b2, out);
}